// Round 13
// baseline (1852.672 us; speedup 1.0000x reference)
//
#include <hip/hip_runtime.h>
#include <hip/hip_bf16.h>
#include <math.h>

// ---------------------------------------------------------------------------
// TransformerNet: 4x TransformerConv (heads=1) + ELU, GlobalAttention pool,
// final linear.
// R1-R11: see history. R12(this): depth-2 software pipeline in attn_fused —
// next chunk's csr_src + k/v gathers issued before current chunk's FMAs
// (double-buffered regs, unroll-2 ping-pong). VALU 40% + HBM 29% showed
// neither pipe saturated: the un-pipelined chunk loop was the limiter.
// ---------------------------------------------------------------------------

typedef __bf16 bf16x8 __attribute__((ext_vector_type(8)));
typedef __bf16 bf16x4 __attribute__((ext_vector_type(4)));
typedef float f32x4 __attribute__((ext_vector_type(4)));

#define GBM 128
#define GBN 128
#define GBK 64

#if __has_builtin(__builtin_amdgcn_global_load_lds)
#define ASYNC_LDS 1
__device__ __forceinline__ void gload16(const __bf16* g, __bf16* l) {
  __builtin_amdgcn_global_load_lds(
      (const __attribute__((address_space(1))) unsigned int*)g,
      (__attribute__((address_space(3))) unsigned int*)l, 16, 0, 0);
}
#endif

// Fused GEMM: A[M,K](bf16) @ Wt[Nc,K]^T + bias -> qkvs[M][Nc] (bf16)
__global__ __launch_bounds__(256) void gemm_mfma_kernel(
    const __bf16* __restrict__ A, const __bf16* __restrict__ Bt,
    const float* __restrict__ bias, __bf16* __restrict__ qkvs,
    int M, int K, int Nc) {
  __shared__ __bf16 As[GBM * 64];
  __shared__ __bf16 Bs[GBN * 64];
  const int tid = threadIdx.x;
  const int wave = tid >> 6;
  const int lane = tid & 63;
  const int quad = lane >> 4;
  const int l16 = lane & 15;
  const int m0 = blockIdx.y * GBM;
  const int n0 = blockIdx.x * GBN;
  const int wm = (wave & 1) * 64;
  const int wn = (wave >> 1) * 64;

  const int r8 = lane >> 3;
  const int sseg = lane & 7;

  f32x4 acc[4][4] = {};

  for (int k0 = 0; k0 < K; k0 += GBK) {
#pragma unroll
    for (int it = 0; it < 4; ++it) {
      const int rbase = wave * 32 + it * 8;
      const int row = rbase + r8;
      const int sw = sseg ^ r8;
      const __bf16* ga = A + (size_t)(m0 + row) * K + k0 + sw * 8;
      const __bf16* gb = Bt + (size_t)(n0 + row) * K + k0 + sw * 8;
#ifdef ASYNC_LDS
      gload16(ga, As + rbase * 64);
      gload16(gb, Bs + rbase * 64);
#else
      *(bf16x8*)(As + row * 64 + sseg * 8) = *(const bf16x8*)ga;
      *(bf16x8*)(Bs + row * 64 + sseg * 8) = *(const bf16x8*)gb;
#endif
    }
    __syncthreads();

#pragma unroll
    for (int ks = 0; ks < 2; ++ks) {
      bf16x8 af[4], bfr[4];
#pragma unroll
      for (int i = 0; i < 4; ++i) {
        const int ra = wm + i * 16 + l16;
        const int rb = wn + i * 16 + l16;
        const int ps = ((ks * 4 + quad) ^ (l16 & 7)) * 8;
        af[i]  = *(const bf16x8*)(As + ra * 64 + ps);
        bfr[i] = *(const bf16x8*)(Bs + rb * 64 + ps);
      }
#pragma unroll
      for (int mi = 0; mi < 4; ++mi)
#pragma unroll
        for (int ni = 0; ni < 4; ++ni)
          acc[mi][ni] = __builtin_amdgcn_mfma_f32_16x16x32_bf16(
              af[mi], bfr[ni], acc[mi][ni], 0, 0, 0);
    }
    __syncthreads();
  }

  float bsv[4];
#pragma unroll
  for (int ni = 0; ni < 4; ++ni) bsv[ni] = bias[n0 + wn + ni * 16 + l16];
#pragma unroll
  for (int mi = 0; mi < 4; ++mi) {
#pragma unroll
    for (int r = 0; r < 4; ++r) {
      int row = m0 + wm + mi * 16 + quad * 4 + r;
      if (row < M) {
        size_t rb = (size_t)row * Nc;
#pragma unroll
        for (int ni = 0; ni < 4; ++ni) {
          int col = n0 + wn + ni * 16 + l16;
          qkvs[rb + col] = (__bf16)(acc[mi][ni][r] + bsv[ni]);
        }
      }
    }
  }
}

// ---- pack weights + biases + x-cast + edge histogram (merged) -------------
#define WTOT 860160
#define BTOT 3456
#define XTOT 320000  // N*128/4 float4 chunks
__global__ void pack_all_kernel(
    const float* W0q, const float* W0k, const float* W0v, const float* W0s,
    const float* b0q, const float* b0k, const float* b0v, const float* b0s,
    const float* W1q, const float* W1k, const float* W1v, const float* W1s,
    const float* b1q, const float* b1k, const float* b1v, const float* b1s,
    const float* W2q, const float* W2k, const float* W2v, const float* W2s,
    const float* b2q, const float* b2k, const float* b2v, const float* b2s,
    const float* W3q, const float* W3k, const float* W3v, const float* W3s,
    const float* b3q, const float* b3k, const float* b3v, const float* b3s,
    const float* __restrict__ x, __bf16* __restrict__ xb,
    __bf16* __restrict__ Wt, float* __restrict__ bcat,
    const int* __restrict__ dst, int* __restrict__ deg, int E) {
  const int t = blockIdx.x * 256 + threadIdx.x;
  if (t < WTOT) {
    int l, local, ksh, fsh;
    if (t < 262144)      { l = 0; local = t;          ksh = 7; fsh = 9; }
    else if (t < 786432) { l = 1; local = t - 262144; ksh = 9; fsh = 8; }
    else if (t < 851968) { l = 2; local = t - 786432; ksh = 8; fsh = 6; }
    else                 { l = 3; local = t - 851968; ksh = 6; fsh = 5; }
    const int K = 1 << ksh, fout = 1 << fsh;
    int c = local >> ksh;
    int kk = local & (K - 1);
    int blk = c >> fsh;
    int j = c & (fout - 1);
    const float* W;
    if (l == 0)      W = blk == 0 ? W0q : blk == 1 ? W0k : blk == 2 ? W0v : W0s;
    else if (l == 1) W = blk == 0 ? W1q : blk == 1 ? W1k : blk == 2 ? W1v : W1s;
    else if (l == 2) W = blk == 0 ? W2q : blk == 1 ? W2k : blk == 2 ? W2v : W2s;
    else             W = blk == 0 ? W3q : blk == 1 ? W3k : blk == 2 ? W3v : W3s;
    Wt[t] = (__bf16)W[((size_t)kk << fsh) + j];
  } else if (t < WTOT + BTOT) {
    int u = t - WTOT;
    int l, local, fsh, boff;
    if (u < 2048)      { l = 0; local = u;        fsh = 9; boff = 0; }
    else if (u < 3072) { l = 1; local = u - 2048; fsh = 8; boff = 2048; }
    else if (u < 3328) { l = 2; local = u - 3072; fsh = 6; boff = 3072; }
    else               { l = 3; local = u - 3328; fsh = 5; boff = 3328; }
    const int fout = 1 << fsh;
    int blk = local >> fsh, j = local & (fout - 1);
    const float* b;
    if (l == 0)      b = blk == 0 ? b0q : blk == 1 ? b0k : blk == 2 ? b0v : b0s;
    else if (l == 1) b = blk == 0 ? b1q : blk == 1 ? b1k : blk == 2 ? b1v : b1s;
    else if (l == 2) b = blk == 0 ? b2q : blk == 1 ? b2k : blk == 2 ? b2v : b2s;
    else             b = blk == 0 ? b3q : blk == 1 ? b3k : blk == 2 ? b3v : b3s;
    bcat[boff + local] = b[j];
  } else if (t < WTOT + BTOT + XTOT) {
    int i = t - (WTOT + BTOT);
    float4 v = ((const float4*)x)[i];
    bf16x4 o;
    o[0] = (__bf16)v.x; o[1] = (__bf16)v.y; o[2] = (__bf16)v.z; o[3] = (__bf16)v.w;
    *(bf16x4*)(xb + (size_t)i * 4) = o;
  } else if (t < WTOT + BTOT + XTOT + E) {
    int e = t - (WTOT + BTOT + XTOT);
    atomicAdd(&deg[dst[e]], 1);
  }
}

// ---------------- CSR build ----------------
__global__ __launch_bounds__(1024) void scan_kernel(const int* __restrict__ deg,
                                                    int* __restrict__ offs, int N) {
  __shared__ int sums[1024];
  const int tid = threadIdx.x;
  const int chunk = (N + 1023) / 1024;
  const int start = tid * chunk;
  int s = 0;
  for (int i = 0; i < chunk; ++i) {
    int idx = start + i;
    if (idx < N) s += deg[idx];
  }
  sums[tid] = s;
  __syncthreads();
  for (int off = 1; off < 1024; off <<= 1) {
    int t = (tid >= off) ? sums[tid - off] : 0;
    __syncthreads();
    sums[tid] += t;
    __syncthreads();
  }
  int run = (tid == 0) ? 0 : sums[tid - 1];
  for (int i = 0; i < chunk; ++i) {
    int idx = start + i;
    if (idx < N) {
      offs[idx] = run;
      run += deg[idx];
    }
  }
  if (tid == 1023) offs[N] = sums[1023];
}

__global__ void scatter_kernel(const int* __restrict__ src, const int* __restrict__ dst,
                               const int* __restrict__ offs, int* __restrict__ cursor,
                               int* __restrict__ csr_src, int E) {
  int e = blockIdx.x * blockDim.x + threadIdx.x;
  if (e >= E) return;
  int d = dst[e];
  int pos = offs[d] + atomicAdd(&cursor[d], 1);
  csr_src[pos] = src[e];
}

// ---------------- fused per-node attention (pipelined, fixed-ref) ----------
// One wave per node, NG=64/LPG groups each stream independent edges.
// Depth-2 software pipeline: next chunk's csr_src + k/v gathers issue before
// current chunk's FMAs (ping-pong reg buffers, unroll-2 folds the parity).
template <int D, int LPG_LOG2, bool GATE>
__global__ __launch_bounds__(256) void attn_fused_kernel(
    const __bf16* __restrict__ qkvs, const int* __restrict__ csr_src,
    const int* __restrict__ offs, __bf16* __restrict__ h_out, int N,
    float scale, const float* __restrict__ Wg, const float* __restrict__ bg,
    float* __restrict__ gate_out) {
  constexpr int LPG = 1 << LPG_LOG2;
  constexpr int NG = 64 / LPG;
  constexpr int NIT = D / (8 * LPG);
  constexpr int LD = 4 * D;
  const int node = (blockIdx.x * 256 + threadIdx.x) >> 6;
  const int lane = threadIdx.x & 63;
  if (node >= N) return;
  const int g = lane >> LPG_LOG2;
  const int l = lane & (LPG - 1);
  const int begin = offs[node];
  const int deg = offs[node + 1] - begin;

  const __bf16* qrow = qkvs + (size_t)node * LD;
  bf16x8 qreg[NIT];
#pragma unroll
  for (int it = 0; it < NIT; ++it)
    qreg[it] = *(const bf16x8*)(qrow + it * LPG * 8 + l * 8);

  float m0 = 0.f;
  float s = 0.f;
  float acc[NIT][8] = {};

  // pipeline buffers (parity-indexed; unroll-2 makes indices compile-time)
  bf16x8 kvb[2][NIT], vvb[2][NIT];

  // prologue: load chunk 0
  {
    const bool v0 = g < deg;
    const int s0 = v0 ? csr_src[begin + g] : 0;
    const __bf16* krow = qkvs + (size_t)s0 * LD + D;
    if (v0) {
#pragma unroll
      for (int it = 0; it < NIT; ++it) {
        kvb[0][it] = *(const bf16x8*)(krow + it * LPG * 8 + l * 8);
        vvb[0][it] = *(const bf16x8*)(krow + D + it * LPG * 8 + l * 8);
      }
    }
  }

  int pb = 0;
#pragma unroll 2
  for (int base = 0; base < deg; base += NG) {
    // ---- issue NEXT chunk's loads (independent of current compute) ----
    const int inext = base + NG + g;
    const bool vn = inext < deg;
    const int sn = vn ? csr_src[begin + inext] : 0;
    const __bf16* krn = qkvs + (size_t)sn * LD + D;
    if (vn) {
#pragma unroll
      for (int it = 0; it < NIT; ++it) {
        kvb[pb ^ 1][it] = *(const bf16x8*)(krn + it * LPG * 8 + l * 8);
        vvb[pb ^ 1][it] = *(const bf16x8*)(krn + D + it * LPG * 8 + l * 8);
      }
    }

    // ---- compute CURRENT chunk ----
    const bool valid = (base + g) < deg;
    float p = 0.f;
    if (valid) {
#pragma unroll
      for (int it = 0; it < NIT; ++it)
#pragma unroll
        for (int j = 0; j < 8; ++j)
          p += (float)qreg[it][j] * (float)kvb[pb][it][j];
    }
#pragma unroll
    for (int off = LPG >> 1; off; off >>= 1) p += __shfl_xor(p, off);
    const float logit = valid ? p * scale : -INFINITY;

    if (base == 0) {  // fixed softmax reference from first chunk
      float mm = logit;
#pragma unroll
      for (int off = LPG; off < 64; off <<= 1)
        mm = fmaxf(mm, __shfl_xor(mm, off));
      m0 = mm;
    }

    const float w = __expf(logit - m0);
    s += w;
    if (valid) {
#pragma unroll
      for (int it = 0; it < NIT; ++it)
#pragma unroll
        for (int j = 0; j < 8; ++j) acc[it][j] += w * (float)vvb[pb][it][j];
    }
    pb ^= 1;
  }

  // cross-group combine
#pragma unroll
  for (int off = LPG; off < 64; off <<= 1) {
    s += __shfl_xor(s, off);
#pragma unroll
    for (int it = 0; it < NIT; ++it)
#pragma unroll
      for (int j = 0; j < 8; ++j) acc[it][j] += __shfl_xor(acc[it][j], off);
  }
  const float inv = (deg > 0) ? (1.0f / s) : 0.f;

  if (g == 0) {
    float rr[NIT][8];
#pragma unroll
    for (int it = 0; it < NIT; ++it) {
      const int f0 = it * LPG * 8 + l * 8;
      bf16x8 sk = *(const bf16x8*)(qrow + 3 * D + f0);
      bf16x8 o;
#pragma unroll
      for (int j = 0; j < 8; ++j) {
        float r = acc[it][j] * inv + (float)sk[j];
        r = (r > 0.f) ? r : expm1f(r);
        rr[it][j] = r;
        o[j] = (__bf16)r;
      }
      *(bf16x8*)(h_out + (size_t)node * D + f0) = o;
    }
    if (GATE) {  // last layer: D == 32, NIT == 1, LPG == 4
      float gp = 0.f;
#pragma unroll
      for (int j = 0; j < 8; ++j) gp += rr[0][j] * Wg[l * 8 + j];
#pragma unroll
      for (int off = 1; off < LPG; off <<= 1) gp += __shfl_xor(gp, off);
      if (l == 0) gate_out[node] = gp + bg[0];
    }
  }
}

// ---------------- pooling (atomic-free, bounds inline) ----------------
__global__ __launch_bounds__(256) void pool_final_kernel(
    const __bf16* __restrict__ h, const float* __restrict__ gate,
    const int* __restrict__ batch, int N, const float* __restrict__ Wf,
    const float* __restrict__ bf_, float* __restrict__ out) {
  __shared__ float red[256];
  __shared__ float pooled_s[32];
  __shared__ float m_s, inv_s;
  __shared__ int sb[2];
  const int g = blockIdx.x;
  const int tid = threadIdx.x;

  if (tid < 2) {
    int target = g + tid;
    int lo = 0, hi = N;
    while (lo < hi) {
      int mid = (lo + hi) >> 1;
      if (batch[mid] < target) lo = mid + 1;
      else hi = mid;
    }
    sb[tid] = lo;
  }
  __syncthreads();
  const int s = sb[0];
  const int e_end = sb[1];

  float m = -INFINITY;
  for (int i = s + tid; i < e_end; i += 256) m = fmaxf(m, gate[i]);
  red[tid] = m;
  __syncthreads();
  for (int off = 128; off; off >>= 1) {
    if (tid < off) red[tid] = fmaxf(red[tid], red[tid + off]);
    __syncthreads();
  }
  if (tid == 0) m_s = red[0];
  __syncthreads();
  m = m_s;

  float ss = 0.f;
  for (int i = s + tid; i < e_end; i += 256) ss += __expf(gate[i] - m);
  red[tid] = ss;
  __syncthreads();
  for (int off = 128; off; off >>= 1) {
    if (tid < off) red[tid] += red[tid + off];
    __syncthreads();
  }
  if (tid == 0) inv_s = (e_end > s) ? (1.0f / red[0]) : 0.f;
  __syncthreads();
  const float inv = inv_s;

  const int f = tid & 31;
  const int grp = tid >> 5;
  float acc = 0.f;
  for (int i = s + grp; i < e_end; i += 8)
    acc += __expf(gate[i] - m) * (float)h[(size_t)i * 32 + f];
  red[tid] = acc;
  __syncthreads();
  if (tid < 32) {
    float a = 0.f;
#pragma unroll
    for (int j = 0; j < 8; ++j) a += red[j * 32 + tid];
    pooled_s[tid] = a * inv;
  }
  __syncthreads();

  if (tid < 9) {
    float o = bf_[tid];
#pragma unroll
    for (int kk = 0; kk < 32; ++kk) o += pooled_s[kk] * Wf[kk * 9 + tid];
    out[g * 9 + tid] = o;
  }
}

// ---------------------------------------------------------------------------
extern "C" void kernel_launch(void* const* d_in, const int* in_sizes, int n_in,
                              void* d_out, int out_size, void* d_ws, size_t ws_size,
                              hipStream_t stream) {
  const int N = in_sizes[2];       // 10000 nodes
  const int E = in_sizes[1] / 2;   // 160000 edges
  const int G = 16;
  const int NP = N + 128;

  const float* x = (const float*)d_in[0];
  const int* ei = (const int*)d_in[1];
  const int* batch = (const int*)d_in[2];
  const int* src = ei;
  const int* dst = ei + E;
  const float* Wg = (const float*)d_in[35];
  const float* bg = (const float*)d_in[36];
  const float* Wf = (const float*)d_in[37];
  const float* bf_ = (const float*)d_in[38];
  float* out = (float*)d_out;

  char* p = (char*)d_ws;
  auto carve = [&](size_t bytes) -> char* {
    char* r = p;
    p += (bytes + 255) & ~(size_t)255;
    return r;
  };
  int* deg = (int*)carve((size_t)2 * N * 4);
  int* cursor = deg + N;
  int* offs = (int*)carve((size_t)(N + 1) * 4);
  int* csr_src = (int*)carve((size_t)E * 4);
  __bf16* Ab = (__bf16*)carve((size_t)NP * 128 * 2);
  __bf16* Wt = (__bf16*)carve((size_t)WTOT * 2);
  float* bcat = (float*)carve(BTOT * 4);
  __bf16* qkvs = (__bf16*)carve((size_t)N * 2048 * 2);
  __bf16* ha = (__bf16*)carve((size_t)NP * 512 * 2);
  __bf16* hb = (__bf16*)carve((size_t)NP * 512 * 2);
  float* gate = (float*)carve((size_t)N * 4);
  (void)ws_size;

  // ---- setup: memset, pack(+hist), scan, scatter ----
  hipMemsetAsync(deg, 0, (size_t)2 * N * 4, stream);
  const float** di = (const float**)d_in;
  pack_all_kernel<<<(WTOT + BTOT + XTOT + E + 255) / 256, 256, 0, stream>>>(
      di[3], di[5], di[7], di[9], di[4], di[6], di[8], di[10],
      di[11], di[13], di[15], di[17], di[12], di[14], di[16], di[18],
      di[19], di[21], di[23], di[25], di[20], di[22], di[24], di[26],
      di[27], di[29], di[31], di[33], di[28], di[30], di[32], di[34],
      x, Ab, Wt, bcat, dst, deg, E);
  scan_kernel<<<1, 1024, 0, stream>>>(deg, offs, N);
  scatter_kernel<<<(E + 255) / 256, 256, 0, stream>>>(src, dst, offs, cursor, csr_src, E);

  // ---- layers ----
  const int fins[4] = {128, 512, 256, 64};
  const int fouts[4] = {512, 256, 64, 32};
  const size_t woffs[4] = {0, 262144, 786432, 851968};
  const int boffs[4] = {0, 2048, 3072, 3328};
  const __bf16* hin = Ab;
  __bf16* houts[4] = {ha, hb, ha, hb};
  const int agrid = ((size_t)N * 64 + 255) / 256;

  for (int l = 0; l < 4; ++l) {
    const int fin = fins[l], fout = fouts[l];
    const int Nc = 4 * fout;
    __bf16* hout = houts[l];

    dim3 grid(Nc / GBN, (N + GBM - 1) / GBM);
    gemm_mfma_kernel<<<grid, 256, 0, stream>>>(hin, Wt + woffs[l], bcat + boffs[l],
                                               qkvs, N, fin, Nc);

    float scale = 1.0f / sqrtf((float)fout);
    if (l == 0) {
      attn_fused_kernel<512, 4, false><<<agrid, 256, 0, stream>>>(
          qkvs, csr_src, offs, hout, N, scale, nullptr, nullptr, nullptr);
    } else if (l == 1) {
      attn_fused_kernel<256, 4, false><<<agrid, 256, 0, stream>>>(
          qkvs, csr_src, offs, hout, N, scale, nullptr, nullptr, nullptr);
    } else if (l == 2) {
      attn_fused_kernel<64, 3, false><<<agrid, 256, 0, stream>>>(
          qkvs, csr_src, offs, hout, N, scale, nullptr, nullptr, nullptr);
    } else {
      attn_fused_kernel<32, 2, true><<<agrid, 256, 0, stream>>>(
          qkvs, csr_src, offs, hout, N, scale, Wg, bg, gate);
    }
    hin = hout;
  }

  // ---- pooling ----
  pool_final_kernel<<<G, 256, 0, stream>>>(hin, gate, batch, N, Wf, bf_, out);
}

// Round 14
// 350.825 us; speedup vs baseline: 5.2809x; 5.2809x over previous
//
#include <hip/hip_runtime.h>
#include <hip/hip_bf16.h>
#include <math.h>

// ---------------------------------------------------------------------------
// TransformerNet: 4x TransformerConv (heads=1) + ELU, GlobalAttention pool,
// final linear.
// R1-R11: see history. R12 FAILED (20x regression): parity-indexed register
// ping-pong buffers spilled to scratch (dynamic-trip loop defeated SSA
// promotion). R13(this): revert attn_fused to R11 straight-line form; let
// the compiler unroll the chunk loop (removed explicit unroll-1).
// ---------------------------------------------------------------------------

typedef __bf16 bf16x8 __attribute__((ext_vector_type(8)));
typedef __bf16 bf16x4 __attribute__((ext_vector_type(4)));
typedef float f32x4 __attribute__((ext_vector_type(4)));

#define GBM 128
#define GBN 128
#define GBK 64

#if __has_builtin(__builtin_amdgcn_global_load_lds)
#define ASYNC_LDS 1
__device__ __forceinline__ void gload16(const __bf16* g, __bf16* l) {
  __builtin_amdgcn_global_load_lds(
      (const __attribute__((address_space(1))) unsigned int*)g,
      (__attribute__((address_space(3))) unsigned int*)l, 16, 0, 0);
}
#endif

// Fused GEMM: A[M,K](bf16) @ Wt[Nc,K]^T + bias -> qkvs[M][Nc] (bf16)
__global__ __launch_bounds__(256) void gemm_mfma_kernel(
    const __bf16* __restrict__ A, const __bf16* __restrict__ Bt,
    const float* __restrict__ bias, __bf16* __restrict__ qkvs,
    int M, int K, int Nc) {
  __shared__ __bf16 As[GBM * 64];
  __shared__ __bf16 Bs[GBN * 64];
  const int tid = threadIdx.x;
  const int wave = tid >> 6;
  const int lane = tid & 63;
  const int quad = lane >> 4;
  const int l16 = lane & 15;
  const int m0 = blockIdx.y * GBM;
  const int n0 = blockIdx.x * GBN;
  const int wm = (wave & 1) * 64;
  const int wn = (wave >> 1) * 64;

  const int r8 = lane >> 3;
  const int sseg = lane & 7;

  f32x4 acc[4][4] = {};

  for (int k0 = 0; k0 < K; k0 += GBK) {
#pragma unroll
    for (int it = 0; it < 4; ++it) {
      const int rbase = wave * 32 + it * 8;
      const int row = rbase + r8;
      const int sw = sseg ^ r8;
      const __bf16* ga = A + (size_t)(m0 + row) * K + k0 + sw * 8;
      const __bf16* gb = Bt + (size_t)(n0 + row) * K + k0 + sw * 8;
#ifdef ASYNC_LDS
      gload16(ga, As + rbase * 64);
      gload16(gb, Bs + rbase * 64);
#else
      *(bf16x8*)(As + row * 64 + sseg * 8) = *(const bf16x8*)ga;
      *(bf16x8*)(Bs + row * 64 + sseg * 8) = *(const bf16x8*)gb;
#endif
    }
    __syncthreads();

#pragma unroll
    for (int ks = 0; ks < 2; ++ks) {
      bf16x8 af[4], bfr[4];
#pragma unroll
      for (int i = 0; i < 4; ++i) {
        const int ra = wm + i * 16 + l16;
        const int rb = wn + i * 16 + l16;
        const int ps = ((ks * 4 + quad) ^ (l16 & 7)) * 8;
        af[i]  = *(const bf16x8*)(As + ra * 64 + ps);
        bfr[i] = *(const bf16x8*)(Bs + rb * 64 + ps);
      }
#pragma unroll
      for (int mi = 0; mi < 4; ++mi)
#pragma unroll
        for (int ni = 0; ni < 4; ++ni)
          acc[mi][ni] = __builtin_amdgcn_mfma_f32_16x16x32_bf16(
              af[mi], bfr[ni], acc[mi][ni], 0, 0, 0);
    }
    __syncthreads();
  }

  float bsv[4];
#pragma unroll
  for (int ni = 0; ni < 4; ++ni) bsv[ni] = bias[n0 + wn + ni * 16 + l16];
#pragma unroll
  for (int mi = 0; mi < 4; ++mi) {
#pragma unroll
    for (int r = 0; r < 4; ++r) {
      int row = m0 + wm + mi * 16 + quad * 4 + r;
      if (row < M) {
        size_t rb = (size_t)row * Nc;
#pragma unroll
        for (int ni = 0; ni < 4; ++ni) {
          int col = n0 + wn + ni * 16 + l16;
          qkvs[rb + col] = (__bf16)(acc[mi][ni][r] + bsv[ni]);
        }
      }
    }
  }
}

// ---- pack weights + biases + x-cast + edge histogram (merged) -------------
#define WTOT 860160
#define BTOT 3456
#define XTOT 320000  // N*128/4 float4 chunks
__global__ void pack_all_kernel(
    const float* W0q, const float* W0k, const float* W0v, const float* W0s,
    const float* b0q, const float* b0k, const float* b0v, const float* b0s,
    const float* W1q, const float* W1k, const float* W1v, const float* W1s,
    const float* b1q, const float* b1k, const float* b1v, const float* b1s,
    const float* W2q, const float* W2k, const float* W2v, const float* W2s,
    const float* b2q, const float* b2k, const float* b2v, const float* b2s,
    const float* W3q, const float* W3k, const float* W3v, const float* W3s,
    const float* b3q, const float* b3k, const float* b3v, const float* b3s,
    const float* __restrict__ x, __bf16* __restrict__ xb,
    __bf16* __restrict__ Wt, float* __restrict__ bcat,
    const int* __restrict__ dst, int* __restrict__ deg, int E) {
  const int t = blockIdx.x * 256 + threadIdx.x;
  if (t < WTOT) {
    int l, local, ksh, fsh;
    if (t < 262144)      { l = 0; local = t;          ksh = 7; fsh = 9; }
    else if (t < 786432) { l = 1; local = t - 262144; ksh = 9; fsh = 8; }
    else if (t < 851968) { l = 2; local = t - 786432; ksh = 8; fsh = 6; }
    else                 { l = 3; local = t - 851968; ksh = 6; fsh = 5; }
    const int K = 1 << ksh, fout = 1 << fsh;
    int c = local >> ksh;
    int kk = local & (K - 1);
    int blk = c >> fsh;
    int j = c & (fout - 1);
    const float* W;
    if (l == 0)      W = blk == 0 ? W0q : blk == 1 ? W0k : blk == 2 ? W0v : W0s;
    else if (l == 1) W = blk == 0 ? W1q : blk == 1 ? W1k : blk == 2 ? W1v : W1s;
    else if (l == 2) W = blk == 0 ? W2q : blk == 1 ? W2k : blk == 2 ? W2v : W2s;
    else             W = blk == 0 ? W3q : blk == 1 ? W3k : blk == 2 ? W3v : W3s;
    Wt[t] = (__bf16)W[((size_t)kk << fsh) + j];
  } else if (t < WTOT + BTOT) {
    int u = t - WTOT;
    int l, local, fsh, boff;
    if (u < 2048)      { l = 0; local = u;        fsh = 9; boff = 0; }
    else if (u < 3072) { l = 1; local = u - 2048; fsh = 8; boff = 2048; }
    else if (u < 3328) { l = 2; local = u - 3072; fsh = 6; boff = 3072; }
    else               { l = 3; local = u - 3328; fsh = 5; boff = 3328; }
    const int fout = 1 << fsh;
    int blk = local >> fsh, j = local & (fout - 1);
    const float* b;
    if (l == 0)      b = blk == 0 ? b0q : blk == 1 ? b0k : blk == 2 ? b0v : b0s;
    else if (l == 1) b = blk == 0 ? b1q : blk == 1 ? b1k : blk == 2 ? b1v : b1s;
    else if (l == 2) b = blk == 0 ? b2q : blk == 1 ? b2k : blk == 2 ? b2v : b2s;
    else             b = blk == 0 ? b3q : blk == 1 ? b3k : blk == 2 ? b3v : b3s;
    bcat[boff + local] = b[j];
  } else if (t < WTOT + BTOT + XTOT) {
    int i = t - (WTOT + BTOT);
    float4 v = ((const float4*)x)[i];
    bf16x4 o;
    o[0] = (__bf16)v.x; o[1] = (__bf16)v.y; o[2] = (__bf16)v.z; o[3] = (__bf16)v.w;
    *(bf16x4*)(xb + (size_t)i * 4) = o;
  } else if (t < WTOT + BTOT + XTOT + E) {
    int e = t - (WTOT + BTOT + XTOT);
    atomicAdd(&deg[dst[e]], 1);
  }
}

// ---------------- CSR build ----------------
__global__ __launch_bounds__(1024) void scan_kernel(const int* __restrict__ deg,
                                                    int* __restrict__ offs, int N) {
  __shared__ int sums[1024];
  const int tid = threadIdx.x;
  const int chunk = (N + 1023) / 1024;
  const int start = tid * chunk;
  int s = 0;
  for (int i = 0; i < chunk; ++i) {
    int idx = start + i;
    if (idx < N) s += deg[idx];
  }
  sums[tid] = s;
  __syncthreads();
  for (int off = 1; off < 1024; off <<= 1) {
    int t = (tid >= off) ? sums[tid - off] : 0;
    __syncthreads();
    sums[tid] += t;
    __syncthreads();
  }
  int run = (tid == 0) ? 0 : sums[tid - 1];
  for (int i = 0; i < chunk; ++i) {
    int idx = start + i;
    if (idx < N) {
      offs[idx] = run;
      run += deg[idx];
    }
  }
  if (tid == 1023) offs[N] = sums[1023];
}

__global__ void scatter_kernel(const int* __restrict__ src, const int* __restrict__ dst,
                               const int* __restrict__ offs, int* __restrict__ cursor,
                               int* __restrict__ csr_src, int E) {
  int e = blockIdx.x * blockDim.x + threadIdx.x;
  if (e >= E) return;
  int d = dst[e];
  int pos = offs[d] + atomicAdd(&cursor[d], 1);
  csr_src[pos] = src[e];
}

// ---------------- fused per-node attention (fixed-ref softmax) -------------
// One wave per node, NG=64/LPG groups each stream independent edges.
// m0 = cross-group max of chunk 0 only; w = exp(logit - m0). k+v loaded
// together. Straight-line loop — NO register ping-pong (R12 spilled).
template <int D, int LPG_LOG2, bool GATE>
__global__ __launch_bounds__(256) void attn_fused_kernel(
    const __bf16* __restrict__ qkvs, const int* __restrict__ csr_src,
    const int* __restrict__ offs, __bf16* __restrict__ h_out, int N,
    float scale, const float* __restrict__ Wg, const float* __restrict__ bg,
    float* __restrict__ gate_out) {
  constexpr int LPG = 1 << LPG_LOG2;
  constexpr int NG = 64 / LPG;
  constexpr int NIT = D / (8 * LPG);
  constexpr int LD = 4 * D;
  const int node = (blockIdx.x * 256 + threadIdx.x) >> 6;
  const int lane = threadIdx.x & 63;
  if (node >= N) return;
  const int g = lane >> LPG_LOG2;
  const int l = lane & (LPG - 1);
  const int begin = offs[node];
  const int deg = offs[node + 1] - begin;

  const __bf16* qrow = qkvs + (size_t)node * LD;
  bf16x8 qreg[NIT];
#pragma unroll
  for (int it = 0; it < NIT; ++it)
    qreg[it] = *(const bf16x8*)(qrow + it * LPG * 8 + l * 8);

  float m0 = 0.f;
  float s = 0.f;
  float acc[NIT][8] = {};

  for (int base = 0; base < deg; base += NG) {
    const int i = base + g;
    const bool valid = i < deg;
    const int sidx = valid ? csr_src[begin + i] : 0;
    const __bf16* krow = qkvs + (size_t)sidx * LD + D;
    bf16x8 kv[NIT], vv[NIT];
    if (valid) {
#pragma unroll
      for (int it = 0; it < NIT; ++it) {
        kv[it] = *(const bf16x8*)(krow + it * LPG * 8 + l * 8);
        vv[it] = *(const bf16x8*)(krow + D + it * LPG * 8 + l * 8);
      }
    }
    float p = 0.f;
    if (valid) {
#pragma unroll
      for (int it = 0; it < NIT; ++it)
#pragma unroll
        for (int j = 0; j < 8; ++j) p += (float)qreg[it][j] * (float)kv[it][j];
    }
#pragma unroll
    for (int off = LPG >> 1; off; off >>= 1) p += __shfl_xor(p, off);
    const float logit = valid ? p * scale : -INFINITY;

    if (base == 0) {  // fixed softmax reference from first chunk
      float mm = logit;
#pragma unroll
      for (int off = LPG; off < 64; off <<= 1)
        mm = fmaxf(mm, __shfl_xor(mm, off));
      m0 = mm;
    }

    const float w = __expf(logit - m0);  // invalid lanes: exp(-inf)=0
    s += w;
    if (valid) {
#pragma unroll
      for (int it = 0; it < NIT; ++it)
#pragma unroll
        for (int j = 0; j < 8; ++j) acc[it][j] += w * (float)vv[it][j];
    }
  }

  // cross-group combine (same l across groups holds same features)
#pragma unroll
  for (int off = LPG; off < 64; off <<= 1) {
    s += __shfl_xor(s, off);
#pragma unroll
    for (int it = 0; it < NIT; ++it)
#pragma unroll
      for (int j = 0; j < 8; ++j) acc[it][j] += __shfl_xor(acc[it][j], off);
  }
  const float inv = (deg > 0) ? (1.0f / s) : 0.f;

  if (g == 0) {
    float rr[NIT][8];
#pragma unroll
    for (int it = 0; it < NIT; ++it) {
      const int f0 = it * LPG * 8 + l * 8;
      bf16x8 sk = *(const bf16x8*)(qrow + 3 * D + f0);
      bf16x8 o;
#pragma unroll
      for (int j = 0; j < 8; ++j) {
        float r = acc[it][j] * inv + (float)sk[j];
        r = (r > 0.f) ? r : expm1f(r);
        rr[it][j] = r;
        o[j] = (__bf16)r;
      }
      *(bf16x8*)(h_out + (size_t)node * D + f0) = o;
    }
    if (GATE) {  // last layer: D == 32, NIT == 1, LPG == 4
      float gp = 0.f;
#pragma unroll
      for (int j = 0; j < 8; ++j) gp += rr[0][j] * Wg[l * 8 + j];
#pragma unroll
      for (int off = 1; off < LPG; off <<= 1) gp += __shfl_xor(gp, off);
      if (l == 0) gate_out[node] = gp + bg[0];
    }
  }
}

// ---------------- pooling (atomic-free, bounds inline) ----------------
__global__ __launch_bounds__(256) void pool_final_kernel(
    const __bf16* __restrict__ h, const float* __restrict__ gate,
    const int* __restrict__ batch, int N, const float* __restrict__ Wf,
    const float* __restrict__ bf_, float* __restrict__ out) {
  __shared__ float red[256];
  __shared__ float pooled_s[32];
  __shared__ float m_s, inv_s;
  __shared__ int sb[2];
  const int g = blockIdx.x;
  const int tid = threadIdx.x;

  if (tid < 2) {
    int target = g + tid;
    int lo = 0, hi = N;
    while (lo < hi) {
      int mid = (lo + hi) >> 1;
      if (batch[mid] < target) lo = mid + 1;
      else hi = mid;
    }
    sb[tid] = lo;
  }
  __syncthreads();
  const int s = sb[0];
  const int e_end = sb[1];

  float m = -INFINITY;
  for (int i = s + tid; i < e_end; i += 256) m = fmaxf(m, gate[i]);
  red[tid] = m;
  __syncthreads();
  for (int off = 128; off; off >>= 1) {
    if (tid < off) red[tid] = fmaxf(red[tid], red[tid + off]);
    __syncthreads();
  }
  if (tid == 0) m_s = red[0];
  __syncthreads();
  m = m_s;

  float ss = 0.f;
  for (int i = s + tid; i < e_end; i += 256) ss += __expf(gate[i] - m);
  red[tid] = ss;
  __syncthreads();
  for (int off = 128; off; off >>= 1) {
    if (tid < off) red[tid] += red[tid + off];
    __syncthreads();
  }
  if (tid == 0) inv_s = (e_end > s) ? (1.0f / red[0]) : 0.f;
  __syncthreads();
  const float inv = inv_s;

  const int f = tid & 31;
  const int grp = tid >> 5;
  float acc = 0.f;
  for (int i = s + grp; i < e_end; i += 8)
    acc += __expf(gate[i] - m) * (float)h[(size_t)i * 32 + f];
  red[tid] = acc;
  __syncthreads();
  if (tid < 32) {
    float a = 0.f;
#pragma unroll
    for (int j = 0; j < 8; ++j) a += red[j * 32 + tid];
    pooled_s[tid] = a * inv;
  }
  __syncthreads();

  if (tid < 9) {
    float o = bf_[tid];
#pragma unroll
    for (int kk = 0; kk < 32; ++kk) o += pooled_s[kk] * Wf[kk * 9 + tid];
    out[g * 9 + tid] = o;
  }
}

// ---------------------------------------------------------------------------
extern "C" void kernel_launch(void* const* d_in, const int* in_sizes, int n_in,
                              void* d_out, int out_size, void* d_ws, size_t ws_size,
                              hipStream_t stream) {
  const int N = in_sizes[2];       // 10000 nodes
  const int E = in_sizes[1] / 2;   // 160000 edges
  const int G = 16;
  const int NP = N + 128;

  const float* x = (const float*)d_in[0];
  const int* ei = (const int*)d_in[1];
  const int* batch = (const int*)d_in[2];
  const int* src = ei;
  const int* dst = ei + E;
  const float* Wg = (const float*)d_in[35];
  const float* bg = (const float*)d_in[36];
  const float* Wf = (const float*)d_in[37];
  const float* bf_ = (const float*)d_in[38];
  float* out = (float*)d_out;

  char* p = (char*)d_ws;
  auto carve = [&](size_t bytes) -> char* {
    char* r = p;
    p += (bytes + 255) & ~(size_t)255;
    return r;
  };
  int* deg = (int*)carve((size_t)2 * N * 4);
  int* cursor = deg + N;
  int* offs = (int*)carve((size_t)(N + 1) * 4);
  int* csr_src = (int*)carve((size_t)E * 4);
  __bf16* Ab = (__bf16*)carve((size_t)NP * 128 * 2);
  __bf16* Wt = (__bf16*)carve((size_t)WTOT * 2);
  float* bcat = (float*)carve(BTOT * 4);
  __bf16* qkvs = (__bf16*)carve((size_t)N * 2048 * 2);
  __bf16* ha = (__bf16*)carve((size_t)NP * 512 * 2);
  __bf16* hb = (__bf16*)carve((size_t)NP * 512 * 2);
  float* gate = (float*)carve((size_t)N * 4);
  (void)ws_size;

  // ---- setup: memset, pack(+hist), scan, scatter ----
  hipMemsetAsync(deg, 0, (size_t)2 * N * 4, stream);
  const float** di = (const float**)d_in;
  pack_all_kernel<<<(WTOT + BTOT + XTOT + E + 255) / 256, 256, 0, stream>>>(
      di[3], di[5], di[7], di[9], di[4], di[6], di[8], di[10],
      di[11], di[13], di[15], di[17], di[12], di[14], di[16], di[18],
      di[19], di[21], di[23], di[25], di[20], di[22], di[24], di[26],
      di[27], di[29], di[31], di[33], di[28], di[30], di[32], di[34],
      x, Ab, Wt, bcat, dst, deg, E);
  scan_kernel<<<1, 1024, 0, stream>>>(deg, offs, N);
  scatter_kernel<<<(E + 255) / 256, 256, 0, stream>>>(src, dst, offs, cursor, csr_src, E);

  // ---- layers ----
  const int fins[4] = {128, 512, 256, 64};
  const int fouts[4] = {512, 256, 64, 32};
  const size_t woffs[4] = {0, 262144, 786432, 851968};
  const int boffs[4] = {0, 2048, 3072, 3328};
  const __bf16* hin = Ab;
  __bf16* houts[4] = {ha, hb, ha, hb};
  const int agrid = ((size_t)N * 64 + 255) / 256;

  for (int l = 0; l < 4; ++l) {
    const int fin = fins[l], fout = fouts[l];
    const int Nc = 4 * fout;
    __bf16* hout = houts[l];

    dim3 grid(Nc / GBN, (N + GBM - 1) / GBM);
    gemm_mfma_kernel<<<grid, 256, 0, stream>>>(hin, Wt + woffs[l], bcat + boffs[l],
                                               qkvs, N, fin, Nc);

    float scale = 1.0f / sqrtf((float)fout);
    if (l == 0) {
      attn_fused_kernel<512, 4, false><<<agrid, 256, 0, stream>>>(
          qkvs, csr_src, offs, hout, N, scale, nullptr, nullptr, nullptr);
    } else if (l == 1) {
      attn_fused_kernel<256, 4, false><<<agrid, 256, 0, stream>>>(
          qkvs, csr_src, offs, hout, N, scale, nullptr, nullptr, nullptr);
    } else if (l == 2) {
      attn_fused_kernel<64, 3, false><<<agrid, 256, 0, stream>>>(
          qkvs, csr_src, offs, hout, N, scale, nullptr, nullptr, nullptr);
    } else {
      attn_fused_kernel<32, 2, true><<<agrid, 256, 0, stream>>>(
          qkvs, csr_src, offs, hout, N, scale, Wg, bg, gate);
    }
    hin = hout;
  }

  // ---- pooling ----
  pool_final_kernel<<<G, 256, 0, stream>>>(hin, gate, batch, N, Wf, bf_, out);
}

// Round 15
// 342.554 us; speedup vs baseline: 5.4084x; 1.0241x over previous
//
#include <hip/hip_runtime.h>
#include <hip/hip_bf16.h>
#include <math.h>

// ---------------------------------------------------------------------------
// TransformerNet: 4x TransformerConv (heads=1) + ELU, GlobalAttention pool,
// final linear.
// R1-R13: see history. R14(this): packed math in attn_fused —
// k-dot via v_dot2_f32_bf16 (1 inst per bf16 pair vs 2 cvt + 2 fma),
// v-accumulate as f32x2 (v_pk_fma_f32). attn<512> was VALU-tilted
// (47.9% VALU / 34.5% HBM); structure unchanged from the known-good R13.
// ---------------------------------------------------------------------------

typedef __bf16 bf16x8 __attribute__((ext_vector_type(8)));
typedef __bf16 bf16x4 __attribute__((ext_vector_type(4)));
typedef __bf16 bf16x2 __attribute__((ext_vector_type(2)));
typedef float f32x4 __attribute__((ext_vector_type(4)));
typedef float f32x2 __attribute__((ext_vector_type(2)));

#define GBM 128
#define GBN 128
#define GBK 64

#if __has_builtin(__builtin_amdgcn_global_load_lds)
#define ASYNC_LDS 1
__device__ __forceinline__ void gload16(const __bf16* g, __bf16* l) {
  __builtin_amdgcn_global_load_lds(
      (const __attribute__((address_space(1))) unsigned int*)g,
      (__attribute__((address_space(3))) unsigned int*)l, 16, 0, 0);
}
#endif

#if __has_builtin(__builtin_amdgcn_fdot2_f32_bf16)
#define HAS_BF16_DOT2 1
#endif

// Fused GEMM: A[M,K](bf16) @ Wt[Nc,K]^T + bias -> qkvs[M][Nc] (bf16)
__global__ __launch_bounds__(256) void gemm_mfma_kernel(
    const __bf16* __restrict__ A, const __bf16* __restrict__ Bt,
    const float* __restrict__ bias, __bf16* __restrict__ qkvs,
    int M, int K, int Nc) {
  __shared__ __bf16 As[GBM * 64];
  __shared__ __bf16 Bs[GBN * 64];
  const int tid = threadIdx.x;
  const int wave = tid >> 6;
  const int lane = tid & 63;
  const int quad = lane >> 4;
  const int l16 = lane & 15;
  const int m0 = blockIdx.y * GBM;
  const int n0 = blockIdx.x * GBN;
  const int wm = (wave & 1) * 64;
  const int wn = (wave >> 1) * 64;

  const int r8 = lane >> 3;
  const int sseg = lane & 7;

  f32x4 acc[4][4] = {};

  for (int k0 = 0; k0 < K; k0 += GBK) {
#pragma unroll
    for (int it = 0; it < 4; ++it) {
      const int rbase = wave * 32 + it * 8;
      const int row = rbase + r8;
      const int sw = sseg ^ r8;
      const __bf16* ga = A + (size_t)(m0 + row) * K + k0 + sw * 8;
      const __bf16* gb = Bt + (size_t)(n0 + row) * K + k0 + sw * 8;
#ifdef ASYNC_LDS
      gload16(ga, As + rbase * 64);
      gload16(gb, Bs + rbase * 64);
#else
      *(bf16x8*)(As + row * 64 + sseg * 8) = *(const bf16x8*)ga;
      *(bf16x8*)(Bs + row * 64 + sseg * 8) = *(const bf16x8*)gb;
#endif
    }
    __syncthreads();

#pragma unroll
    for (int ks = 0; ks < 2; ++ks) {
      bf16x8 af[4], bfr[4];
#pragma unroll
      for (int i = 0; i < 4; ++i) {
        const int ra = wm + i * 16 + l16;
        const int rb = wn + i * 16 + l16;
        const int ps = ((ks * 4 + quad) ^ (l16 & 7)) * 8;
        af[i]  = *(const bf16x8*)(As + ra * 64 + ps);
        bfr[i] = *(const bf16x8*)(Bs + rb * 64 + ps);
      }
#pragma unroll
      for (int mi = 0; mi < 4; ++mi)
#pragma unroll
        for (int ni = 0; ni < 4; ++ni)
          acc[mi][ni] = __builtin_amdgcn_mfma_f32_16x16x32_bf16(
              af[mi], bfr[ni], acc[mi][ni], 0, 0, 0);
    }
    __syncthreads();
  }

  float bsv[4];
#pragma unroll
  for (int ni = 0; ni < 4; ++ni) bsv[ni] = bias[n0 + wn + ni * 16 + l16];
#pragma unroll
  for (int mi = 0; mi < 4; ++mi) {
#pragma unroll
    for (int r = 0; r < 4; ++r) {
      int row = m0 + wm + mi * 16 + quad * 4 + r;
      if (row < M) {
        size_t rb = (size_t)row * Nc;
#pragma unroll
        for (int ni = 0; ni < 4; ++ni) {
          int col = n0 + wn + ni * 16 + l16;
          qkvs[rb + col] = (__bf16)(acc[mi][ni][r] + bsv[ni]);
        }
      }
    }
  }
}

// ---- pack weights + biases + x-cast + edge histogram (merged) -------------
#define WTOT 860160
#define BTOT 3456
#define XTOT 320000  // N*128/4 float4 chunks
__global__ void pack_all_kernel(
    const float* W0q, const float* W0k, const float* W0v, const float* W0s,
    const float* b0q, const float* b0k, const float* b0v, const float* b0s,
    const float* W1q, const float* W1k, const float* W1v, const float* W1s,
    const float* b1q, const float* b1k, const float* b1v, const float* b1s,
    const float* W2q, const float* W2k, const float* W2v, const float* W2s,
    const float* b2q, const float* b2k, const float* b2v, const float* b2s,
    const float* W3q, const float* W3k, const float* W3v, const float* W3s,
    const float* b3q, const float* b3k, const float* b3v, const float* b3s,
    const float* __restrict__ x, __bf16* __restrict__ xb,
    __bf16* __restrict__ Wt, float* __restrict__ bcat,
    const int* __restrict__ dst, int* __restrict__ deg, int E) {
  const int t = blockIdx.x * 256 + threadIdx.x;
  if (t < WTOT) {
    int l, local, ksh, fsh;
    if (t < 262144)      { l = 0; local = t;          ksh = 7; fsh = 9; }
    else if (t < 786432) { l = 1; local = t - 262144; ksh = 9; fsh = 8; }
    else if (t < 851968) { l = 2; local = t - 786432; ksh = 8; fsh = 6; }
    else                 { l = 3; local = t - 851968; ksh = 6; fsh = 5; }
    const int K = 1 << ksh, fout = 1 << fsh;
    int c = local >> ksh;
    int kk = local & (K - 1);
    int blk = c >> fsh;
    int j = c & (fout - 1);
    const float* W;
    if (l == 0)      W = blk == 0 ? W0q : blk == 1 ? W0k : blk == 2 ? W0v : W0s;
    else if (l == 1) W = blk == 0 ? W1q : blk == 1 ? W1k : blk == 2 ? W1v : W1s;
    else if (l == 2) W = blk == 0 ? W2q : blk == 1 ? W2k : blk == 2 ? W2v : W2s;
    else             W = blk == 0 ? W3q : blk == 1 ? W3k : blk == 2 ? W3v : W3s;
    Wt[t] = (__bf16)W[((size_t)kk << fsh) + j];
  } else if (t < WTOT + BTOT) {
    int u = t - WTOT;
    int l, local, fsh, boff;
    if (u < 2048)      { l = 0; local = u;        fsh = 9; boff = 0; }
    else if (u < 3072) { l = 1; local = u - 2048; fsh = 8; boff = 2048; }
    else if (u < 3328) { l = 2; local = u - 3072; fsh = 6; boff = 3072; }
    else               { l = 3; local = u - 3328; fsh = 5; boff = 3328; }
    const int fout = 1 << fsh;
    int blk = local >> fsh, j = local & (fout - 1);
    const float* b;
    if (l == 0)      b = blk == 0 ? b0q : blk == 1 ? b0k : blk == 2 ? b0v : b0s;
    else if (l == 1) b = blk == 0 ? b1q : blk == 1 ? b1k : blk == 2 ? b1v : b1s;
    else if (l == 2) b = blk == 0 ? b2q : blk == 1 ? b2k : blk == 2 ? b2v : b2s;
    else             b = blk == 0 ? b3q : blk == 1 ? b3k : blk == 2 ? b3v : b3s;
    bcat[boff + local] = b[j];
  } else if (t < WTOT + BTOT + XTOT) {
    int i = t - (WTOT + BTOT);
    float4 v = ((const float4*)x)[i];
    bf16x4 o;
    o[0] = (__bf16)v.x; o[1] = (__bf16)v.y; o[2] = (__bf16)v.z; o[3] = (__bf16)v.w;
    *(bf16x4*)(xb + (size_t)i * 4) = o;
  } else if (t < WTOT + BTOT + XTOT + E) {
    int e = t - (WTOT + BTOT + XTOT);
    atomicAdd(&deg[dst[e]], 1);
  }
}

// ---------------- CSR build ----------------
__global__ __launch_bounds__(1024) void scan_kernel(const int* __restrict__ deg,
                                                    int* __restrict__ offs, int N) {
  __shared__ int sums[1024];
  const int tid = threadIdx.x;
  const int chunk = (N + 1023) / 1024;
  const int start = tid * chunk;
  int s = 0;
  for (int i = 0; i < chunk; ++i) {
    int idx = start + i;
    if (idx < N) s += deg[idx];
  }
  sums[tid] = s;
  __syncthreads();
  for (int off = 1; off < 1024; off <<= 1) {
    int t = (tid >= off) ? sums[tid - off] : 0;
    __syncthreads();
    sums[tid] += t;
    __syncthreads();
  }
  int run = (tid == 0) ? 0 : sums[tid - 1];
  for (int i = 0; i < chunk; ++i) {
    int idx = start + i;
    if (idx < N) {
      offs[idx] = run;
      run += deg[idx];
    }
  }
  if (tid == 1023) offs[N] = sums[1023];
}

__global__ void scatter_kernel(const int* __restrict__ src, const int* __restrict__ dst,
                               const int* __restrict__ offs, int* __restrict__ cursor,
                               int* __restrict__ csr_src, int E) {
  int e = blockIdx.x * blockDim.x + threadIdx.x;
  if (e >= E) return;
  int d = dst[e];
  int pos = offs[d] + atomicAdd(&cursor[d], 1);
  csr_src[pos] = src[e];
}

// ---------------- fused per-node attention (fixed-ref softmax) -------------
// One wave per node, NG=64/LPG groups each stream independent edges.
// m0 = cross-group max of chunk 0 only; w = exp(logit - m0). k-dot uses
// v_dot2_f32_bf16 (packed pair dot); v-acc uses f32x2 (v_pk_fma_f32).
// Straight-line loop — no register ping-pong (R12 spilled).
template <int D, int LPG_LOG2, bool GATE>
__global__ __launch_bounds__(256) void attn_fused_kernel(
    const __bf16* __restrict__ qkvs, const int* __restrict__ csr_src,
    const int* __restrict__ offs, __bf16* __restrict__ h_out, int N,
    float scale, const float* __restrict__ Wg, const float* __restrict__ bg,
    float* __restrict__ gate_out) {
  constexpr int LPG = 1 << LPG_LOG2;
  constexpr int NG = 64 / LPG;
  constexpr int NIT = D / (8 * LPG);
  constexpr int LD = 4 * D;
  const int node = (blockIdx.x * 256 + threadIdx.x) >> 6;
  const int lane = threadIdx.x & 63;
  if (node >= N) return;
  const int g = lane >> LPG_LOG2;
  const int l = lane & (LPG - 1);
  const int begin = offs[node];
  const int deg = offs[node + 1] - begin;

  const __bf16* qrow = qkvs + (size_t)node * LD;
  bf16x8 qreg[NIT];
#pragma unroll
  for (int it = 0; it < NIT; ++it)
    qreg[it] = *(const bf16x8*)(qrow + it * LPG * 8 + l * 8);

  float m0 = 0.f;
  float s = 0.f;
  f32x2 acc[NIT][4] = {};

  for (int base = 0; base < deg; base += NG) {
    const int i = base + g;
    const bool valid = i < deg;
    const int sidx = valid ? csr_src[begin + i] : 0;
    const __bf16* krow = qkvs + (size_t)sidx * LD + D;
    bf16x8 kv[NIT], vv[NIT];
    if (valid) {
#pragma unroll
      for (int it = 0; it < NIT; ++it) {
        kv[it] = *(const bf16x8*)(krow + it * LPG * 8 + l * 8);
        vv[it] = *(const bf16x8*)(krow + D + it * LPG * 8 + l * 8);
      }
    }
    float p = 0.f;
    if (valid) {
#ifdef HAS_BF16_DOT2
#pragma unroll
      for (int it = 0; it < NIT; ++it)
#pragma unroll
        for (int j2 = 0; j2 < 4; ++j2) {
          bf16x2 qa; qa[0] = qreg[it][2 * j2]; qa[1] = qreg[it][2 * j2 + 1];
          bf16x2 ka; ka[0] = kv[it][2 * j2];   ka[1] = kv[it][2 * j2 + 1];
          p = __builtin_amdgcn_fdot2_f32_bf16(qa, ka, p, false);
        }
#else
#pragma unroll
      for (int it = 0; it < NIT; ++it)
#pragma unroll
        for (int j = 0; j < 8; ++j) p += (float)qreg[it][j] * (float)kv[it][j];
#endif
    }
#pragma unroll
    for (int off = LPG >> 1; off; off >>= 1) p += __shfl_xor(p, off);
    const float logit = valid ? p * scale : -INFINITY;

    if (base == 0) {  // fixed softmax reference from first chunk
      float mm = logit;
#pragma unroll
      for (int off = LPG; off < 64; off <<= 1)
        mm = fmaxf(mm, __shfl_xor(mm, off));
      m0 = mm;
    }

    const float w = __expf(logit - m0);  // invalid lanes: exp(-inf)=0
    s += w;
    if (valid) {
      f32x2 w2; w2[0] = w; w2[1] = w;
#pragma unroll
      for (int it = 0; it < NIT; ++it)
#pragma unroll
        for (int j2 = 0; j2 < 4; ++j2) {
          f32x2 vf;
          vf[0] = (float)vv[it][2 * j2];
          vf[1] = (float)vv[it][2 * j2 + 1];
          acc[it][j2] += w2 * vf;  // v_pk_fma_f32
        }
    }
  }

  // cross-group combine (same l across groups holds same features)
#pragma unroll
  for (int off = LPG; off < 64; off <<= 1) {
    s += __shfl_xor(s, off);
#pragma unroll
    for (int it = 0; it < NIT; ++it)
#pragma unroll
      for (int j2 = 0; j2 < 4; ++j2) {
        acc[it][j2][0] += __shfl_xor(acc[it][j2][0], off);
        acc[it][j2][1] += __shfl_xor(acc[it][j2][1], off);
      }
  }
  const float inv = (deg > 0) ? (1.0f / s) : 0.f;

  if (g == 0) {
    float rr[NIT][8];
#pragma unroll
    for (int it = 0; it < NIT; ++it) {
      const int f0 = it * LPG * 8 + l * 8;
      bf16x8 sk = *(const bf16x8*)(qrow + 3 * D + f0);
      bf16x8 o;
#pragma unroll
      for (int j2 = 0; j2 < 4; ++j2) {
        float r0 = acc[it][j2][0] * inv + (float)sk[2 * j2];
        float r1 = acc[it][j2][1] * inv + (float)sk[2 * j2 + 1];
        r0 = (r0 > 0.f) ? r0 : expm1f(r0);
        r1 = (r1 > 0.f) ? r1 : expm1f(r1);
        rr[it][2 * j2] = r0;
        rr[it][2 * j2 + 1] = r1;
        o[2 * j2] = (__bf16)r0;
        o[2 * j2 + 1] = (__bf16)r1;
      }
      *(bf16x8*)(h_out + (size_t)node * D + f0) = o;
    }
    if (GATE) {  // last layer: D == 32, NIT == 1, LPG == 4
      float gp = 0.f;
#pragma unroll
      for (int j = 0; j < 8; ++j) gp += rr[0][j] * Wg[l * 8 + j];
#pragma unroll
      for (int off = 1; off < LPG; off <<= 1) gp += __shfl_xor(gp, off);
      if (l == 0) gate_out[node] = gp + bg[0];
    }
  }
}

// ---------------- pooling (atomic-free, bounds inline) ----------------
__global__ __launch_bounds__(256) void pool_final_kernel(
    const __bf16* __restrict__ h, const float* __restrict__ gate,
    const int* __restrict__ batch, int N, const float* __restrict__ Wf,
    const float* __restrict__ bf_, float* __restrict__ out) {
  __shared__ float red[256];
  __shared__ float pooled_s[32];
  __shared__ float m_s, inv_s;
  __shared__ int sb[2];
  const int g = blockIdx.x;
  const int tid = threadIdx.x;

  if (tid < 2) {
    int target = g + tid;
    int lo = 0, hi = N;
    while (lo < hi) {
      int mid = (lo + hi) >> 1;
      if (batch[mid] < target) lo = mid + 1;
      else hi = mid;
    }
    sb[tid] = lo;
  }
  __syncthreads();
  const int s = sb[0];
  const int e_end = sb[1];

  float m = -INFINITY;
  for (int i = s + tid; i < e_end; i += 256) m = fmaxf(m, gate[i]);
  red[tid] = m;
  __syncthreads();
  for (int off = 128; off; off >>= 1) {
    if (tid < off) red[tid] = fmaxf(red[tid], red[tid + off]);
    __syncthreads();
  }
  if (tid == 0) m_s = red[0];
  __syncthreads();
  m = m_s;

  float ss = 0.f;
  for (int i = s + tid; i < e_end; i += 256) ss += __expf(gate[i] - m);
  red[tid] = ss;
  __syncthreads();
  for (int off = 128; off; off >>= 1) {
    if (tid < off) red[tid] += red[tid + off];
    __syncthreads();
  }
  if (tid == 0) inv_s = (e_end > s) ? (1.0f / red[0]) : 0.f;
  __syncthreads();
  const float inv = inv_s;

  const int f = tid & 31;
  const int grp = tid >> 5;
  float acc = 0.f;
  for (int i = s + grp; i < e_end; i += 8)
    acc += __expf(gate[i] - m) * (float)h[(size_t)i * 32 + f];
  red[tid] = acc;
  __syncthreads();
  if (tid < 32) {
    float a = 0.f;
#pragma unroll
    for (int j = 0; j < 8; ++j) a += red[j * 32 + tid];
    pooled_s[tid] = a * inv;
  }
  __syncthreads();

  if (tid < 9) {
    float o = bf_[tid];
#pragma unroll
    for (int kk = 0; kk < 32; ++kk) o += pooled_s[kk] * Wf[kk * 9 + tid];
    out[g * 9 + tid] = o;
  }
}

// ---------------------------------------------------------------------------
extern "C" void kernel_launch(void* const* d_in, const int* in_sizes, int n_in,
                              void* d_out, int out_size, void* d_ws, size_t ws_size,
                              hipStream_t stream) {
  const int N = in_sizes[2];       // 10000 nodes
  const int E = in_sizes[1] / 2;   // 160000 edges
  const int G = 16;
  const int NP = N + 128;

  const float* x = (const float*)d_in[0];
  const int* ei = (const int*)d_in[1];
  const int* batch = (const int*)d_in[2];
  const int* src = ei;
  const int* dst = ei + E;
  const float* Wg = (const float*)d_in[35];
  const float* bg = (const float*)d_in[36];
  const float* Wf = (const float*)d_in[37];
  const float* bf_ = (const float*)d_in[38];
  float* out = (float*)d_out;

  char* p = (char*)d_ws;
  auto carve = [&](size_t bytes) -> char* {
    char* r = p;
    p += (bytes + 255) & ~(size_t)255;
    return r;
  };
  int* deg = (int*)carve((size_t)2 * N * 4);
  int* cursor = deg + N;
  int* offs = (int*)carve((size_t)(N + 1) * 4);
  int* csr_src = (int*)carve((size_t)E * 4);
  __bf16* Ab = (__bf16*)carve((size_t)NP * 128 * 2);
  __bf16* Wt = (__bf16*)carve((size_t)WTOT * 2);
  float* bcat = (float*)carve(BTOT * 4);
  __bf16* qkvs = (__bf16*)carve((size_t)N * 2048 * 2);
  __bf16* ha = (__bf16*)carve((size_t)NP * 512 * 2);
  __bf16* hb = (__bf16*)carve((size_t)NP * 512 * 2);
  float* gate = (float*)carve((size_t)N * 4);
  (void)ws_size;

  // ---- setup: memset, pack(+hist), scan, scatter ----
  hipMemsetAsync(deg, 0, (size_t)2 * N * 4, stream);
  const float** di = (const float**)d_in;
  pack_all_kernel<<<(WTOT + BTOT + XTOT + E + 255) / 256, 256, 0, stream>>>(
      di[3], di[5], di[7], di[9], di[4], di[6], di[8], di[10],
      di[11], di[13], di[15], di[17], di[12], di[14], di[16], di[18],
      di[19], di[21], di[23], di[25], di[20], di[22], di[24], di[26],
      di[27], di[29], di[31], di[33], di[28], di[30], di[32], di[34],
      x, Ab, Wt, bcat, dst, deg, E);
  scan_kernel<<<1, 1024, 0, stream>>>(deg, offs, N);
  scatter_kernel<<<(E + 255) / 256, 256, 0, stream>>>(src, dst, offs, cursor, csr_src, E);

  // ---- layers ----
  const int fins[4] = {128, 512, 256, 64};
  const int fouts[4] = {512, 256, 64, 32};
  const size_t woffs[4] = {0, 262144, 786432, 851968};
  const int boffs[4] = {0, 2048, 3072, 3328};
  const __bf16* hin = Ab;
  __bf16* houts[4] = {ha, hb, ha, hb};
  const int agrid = ((size_t)N * 64 + 255) / 256;

  for (int l = 0; l < 4; ++l) {
    const int fin = fins[l], fout = fouts[l];
    const int Nc = 4 * fout;
    __bf16* hout = houts[l];

    dim3 grid(Nc / GBN, (N + GBM - 1) / GBM);
    gemm_mfma_kernel<<<grid, 256, 0, stream>>>(hin, Wt + woffs[l], bcat + boffs[l],
                                               qkvs, N, fin, Nc);

    float scale = 1.0f / sqrtf((float)fout);
    if (l == 0) {
      attn_fused_kernel<512, 4, false><<<agrid, 256, 0, stream>>>(
          qkvs, csr_src, offs, hout, N, scale, nullptr, nullptr, nullptr);
    } else if (l == 1) {
      attn_fused_kernel<256, 4, false><<<agrid, 256, 0, stream>>>(
          qkvs, csr_src, offs, hout, N, scale, nullptr, nullptr, nullptr);
    } else if (l == 2) {
      attn_fused_kernel<64, 3, false><<<agrid, 256, 0, stream>>>(
          qkvs, csr_src, offs, hout, N, scale, nullptr, nullptr, nullptr);
    } else {
      attn_fused_kernel<32, 2, true><<<agrid, 256, 0, stream>>>(
          qkvs, csr_src, offs, hout, N, scale, Wg, bg, gate);
    }
    hin = hout;
  }

  // ---- pooling ----
  pool_final_kernel<<<G, 256, 0, stream>>>(hin, gate, batch, N, Wf, bf_, out);
}